// Round 6
// baseline (648.441 us; speedup 1.0000x reference)
//
#include <hip/hip_runtime.h>
#include <hip/hip_cooperative_groups.h>
#include <hip/hip_bf16.h>

namespace cg = cooperative_groups;

#define IN_DIM 256
#define HEADS 4
#define HID 64
#define NEG_SLOPE 0.2f

typedef float f32x4 __attribute__((ext_vector_type(4)));
typedef short bf16x8 __attribute__((ext_vector_type(8)));
typedef unsigned short u16x8 __attribute__((ext_vector_type(8)));

__device__ __forceinline__ unsigned short f2bf(float f) {
    unsigned u = __float_as_uint(f);
    unsigned r = u + 0x7fffu + ((u >> 16) & 1u);   // RNE
    return (unsigned short)(r >> 16);
}
__device__ __forceinline__ float bf2f(unsigned short b) {
    return __uint_as_float(((unsigned)b) << 16);
}
__device__ __forceinline__ void gload16(const void* g, void* l) {
    __builtin_amdgcn_global_load_lds(
        (const __attribute__((address_space(1))) unsigned int*)g,
        (__attribute__((address_space(3))) unsigned int*)l, 16, 0, 0);
}

// ---------- 0. cooperative plumbing: zero | casts+hist | blocksums | scan |
// scatter — one dispatch, grid.sync() between phases (device-scope fence).
__global__ __launch_bounds__(256) void plumbing_kernel(
        const float* __restrict__ x, unsigned short* __restrict__ xb, int n8,
        const float* __restrict__ W, unsigned short* __restrict__ wt,
        const int* __restrict__ src, const int* __restrict__ dst,
        int* __restrict__ count, int* __restrict__ bsum,
        int* __restrict__ row_start, int* __restrict__ cursor,
        int* __restrict__ perm_src, int N, int E, int NB) {
    cg::grid_group grid = cg::this_grid();
    const int gsz = gridDim.x * 256;
    const int g0 = blockIdx.x * 256 + threadIdx.x;
    const int tid = threadIdx.x, lane = tid & 63, wv = tid >> 6;
    __shared__ int ws[4];
    __shared__ int boff_s;

    // P0: zero the histogram
    for (int i = g0; i < N; i += gsz) count[i] = 0;
    grid.sync();

    // P1: cast x -> bf16 (8 floats/iter); cast+transpose W; dst histogram
    for (int i = g0; i < n8; i += gsz) {
        const float4* p = (const float4*)x + (size_t)i * 2;
        float4 a = p[0], b = p[1];
        u16x8 o;
        o[0] = f2bf(a.x); o[1] = f2bf(a.y); o[2] = f2bf(a.z); o[3] = f2bf(a.w);
        o[4] = f2bf(b.x); o[5] = f2bf(b.y); o[6] = f2bf(b.z); o[7] = f2bf(b.w);
        *(u16x8*)(xb + (size_t)i * 8) = o;
    }
    for (int i = g0; i < 256 * 256; i += gsz) {
        int n = i & 255, k = i >> 8;
        wt[n * 256 + k] = f2bf(W[k * 256 + n]);
    }
    for (int i = g0; i < E; i += gsz) atomicAdd(&count[dst[i]], 1);
    grid.sync();

    // P2: per-256-chunk sums (NB <= 256 so the P3 offset reduce fits a block)
    for (int c = blockIdx.x; c < NB; c += gridDim.x) {
        int i = c * 256 + tid;
        int v = (i < N) ? count[i] : 0;
        #pragma unroll
        for (int off = 1; off < 64; off <<= 1) v += __shfl_xor(v, off);
        if (lane == 0) ws[wv] = v;
        __syncthreads();
        if (tid == 0) bsum[c] = ws[0] + ws[1] + ws[2] + ws[3];
        __syncthreads();
    }
    grid.sync();

    // P3: exclusive scan -> row_start, cursor (block offset = sum bsum[0..c))
    for (int c = blockIdx.x; c < NB; c += gridDim.x) {
        int bv = (tid < c) ? bsum[tid] : 0;
        #pragma unroll
        for (int off = 1; off < 64; off <<= 1) bv += __shfl_xor(bv, off);
        if (lane == 0) ws[wv] = bv;
        __syncthreads();
        if (tid == 0) boff_s = ws[0] + ws[1] + ws[2] + ws[3];
        __syncthreads();
        int i = c * 256 + tid;
        int v = (i < N) ? count[i] : 0;
        int incl = v;
        #pragma unroll
        for (int off = 1; off < 64; off <<= 1) {
            int t = __shfl_up(incl, off);
            if (lane >= off) incl += t;
        }
        if (lane == 63) ws[wv] = incl;
        __syncthreads();
        int wofs = 0;
        #pragma unroll
        for (int w = 0; w < 4; ++w) if (w < wv) wofs += ws[w];
        int excl = boff_s + wofs + incl - v;
        if (i < N) { row_start[i] = excl; cursor[i] = excl; }
        else if (i == N) row_start[N] = excl;
        __syncthreads();
    }
    grid.sync();

    // P4: scatter src ids into dst-buckets
    for (int i = g0; i < E; i += gsz) {
        int pos = atomicAdd(&cursor[dst[i]], 1);
        perm_src[pos] = src[i];
    }
}

// ---------- 1. MFMA GEMM + fused el/er ----------
// BM=64, BN=256 (full width: A fetched once); 4 waves; wave wv owns cols
// [64*wv, 64*wv+64) == head wv, so el/er computed in-epilogue from f32 acc.
#define BM 64
#define BK 64
__global__ __launch_bounds__(256) void mfma_gemm_kernel(
        const unsigned short* __restrict__ xb, const unsigned short* __restrict__ wt,
        const float* __restrict__ attn_l, const float* __restrict__ attn_r,
        unsigned short* __restrict__ featb, float* __restrict__ el,
        float* __restrict__ er, int N) {
    __shared__ unsigned short As[BM * BK];       // 8 KB
    __shared__ unsigned short Bs[256 * BK];      // 32 KB
    const int tid = threadIdx.x;
    const int lane = tid & 63;
    const int wv = tid >> 6;                     // head / col-block
    const int bm = blockIdx.x * BM;

    f32x4 acc[4][4] = {};

    for (int k0 = 0; k0 < IN_DIM; k0 += BK) {
        #pragma unroll
        for (int r = 0; r < 2; ++r) {            // A: 512 x 16B slots
            int i = r * 256 + tid;
            int row = i >> 3, slot = (i & 7) ^ (row & 7);
            int grow = bm + row; if (grow >= N) grow = N - 1;
            gload16(xb + (size_t)grow * IN_DIM + k0 + slot * 8,
                    (char*)As + (size_t)(r * 256 + (wv << 6)) * 16);
        }
        #pragma unroll
        for (int r = 0; r < 8; ++r) {            // B: 2048 x 16B slots
            int i = r * 256 + tid;
            int row = i >> 3, slot = (i & 7) ^ (row & 7);
            gload16(wt + (size_t)row * IN_DIM + k0 + slot * 8,
                    (char*)Bs + (size_t)(r * 256 + (wv << 6)) * 16);
        }
        __syncthreads();
        #pragma unroll
        for (int kk = 0; kk < 2; ++kk) {
            const int k16 = kk * 4 + (lane >> 4);
            bf16x8 af[4], bg[4];
            #pragma unroll
            for (int m = 0; m < 4; ++m) {
                int row = m * 16 + (lane & 15);
                af[m] = *(const bf16x8*)((const char*)As + row * 128 + ((k16 ^ (row & 7)) << 4));
            }
            #pragma unroll
            for (int n = 0; n < 4; ++n) {
                int row = (wv << 6) + n * 16 + (lane & 15);
                bg[n] = *(const bf16x8*)((const char*)Bs + row * 128 + ((k16 ^ (row & 7)) << 4));
            }
            #pragma unroll
            for (int m = 0; m < 4; ++m)
                #pragma unroll
                for (int n = 0; n < 4; ++n)
                    acc[m][n] = __builtin_amdgcn_mfma_f32_16x16x32_bf16(af[m], bg[n], acc[m][n], 0, 0, 0);
        }
        __syncthreads();
    }

    const int c15 = lane & 15;
    float al0 = attn_l[(wv << 6) + c15],      ar0 = attn_r[(wv << 6) + c15];
    float al1 = attn_l[(wv << 6) + 16 + c15], ar1 = attn_r[(wv << 6) + 16 + c15];
    float al2 = attn_l[(wv << 6) + 32 + c15], ar2 = attn_r[(wv << 6) + 32 + c15];
    float al3 = attn_l[(wv << 6) + 48 + c15], ar3 = attn_r[(wv << 6) + 48 + c15];

    #pragma unroll
    for (int m = 0; m < 4; ++m) {
        #pragma unroll
        for (int j = 0; j < 4; ++j) {
            int row = bm + m * 16 + ((lane >> 4) << 2) + j;
            bool ok = row < N;
            if (ok) {
                #pragma unroll
                for (int n = 0; n < 4; ++n)
                    featb[(size_t)row * IN_DIM + (wv << 6) + n * 16 + c15] = f2bf(acc[m][n][j]);
            }
            float pl = acc[m][0][j] * al0 + acc[m][1][j] * al1 + acc[m][2][j] * al2 + acc[m][3][j] * al3;
            float pr = acc[m][0][j] * ar0 + acc[m][1][j] * ar1 + acc[m][2][j] * ar2 + acc[m][3][j] * ar3;
            #pragma unroll
            for (int off = 1; off < 16; off <<= 1) {
                pl += __shfl_xor(pl, off);
                pr += __shfl_xor(pr, off);
            }
            if (ok && c15 == 0) {
                el[row * HEADS + wv] = pl;
                er[row * HEADS + wv] = pr;
            }
        }
    }
}

// ---------- 2. fused softmax + aggregate (single pass, no max-shift) -------
// Logits tiny (|v|<~3), exp safe unshifted; softmax shift-invariant.
// Lane=(h=lane>>4, q=lane&15); 1 ushort4 (8B) coalesced feat load per edge;
// 4-way unroll (R4-proven: 24 VGPR, 68% occ) + int4 perm loads.
#define AGG_ONE(s) do {                                             \
    float v_ = el[(s) * HEADS + h] + erh;                           \
    v_ = v_ > 0.f ? v_ : NEG_SLOPE * v_;                            \
    float e_ = __expf(v_);                                          \
    dh += e_;                                                       \
    ushort4 fv_ = *(const ushort4*)(featb + ((size_t)(s) << 8) + col); \
    ax += e_ * bf2f(fv_.x); ay += e_ * bf2f(fv_.y);                 \
    az += e_ * bf2f(fv_.z); aw += e_ * bf2f(fv_.w); } while (0)

__global__ __launch_bounds__(256) void node_aggregate_kernel(
        const unsigned short* __restrict__ featb, const float* __restrict__ el,
        const float* __restrict__ er, const int* __restrict__ row_start,
        const int* __restrict__ perm_src, float* __restrict__ out, int N) {
    int wid = blockIdx.x * 4 + (threadIdx.x >> 6);
    int lane = threadIdx.x & 63;
    if (wid >= N) return;
    const int beg = row_start[wid], end = row_start[wid + 1];
    if (beg == end) {
        if (lane < 16) *(float4*)(out + (size_t)wid * HID + lane * 4) = make_float4(0.f, 0.f, 0.f, 0.f);
        return;
    }
    const int h = lane >> 4;
    const float erh = er[wid * HEADS + h];
    const int col = lane * 4;

    float dh = 0.f, ax = 0.f, ay = 0.f, az = 0.f, aw = 0.f;
    int p = beg;
    while (p < end && (p & 3)) { AGG_ONE(perm_src[p]); ++p; }
    for (; p + 4 <= end; p += 4) {
        int4 pa = *(const int4*)(perm_src + p);
        int s0 = pa.x, s1 = pa.y, s2 = pa.z, s3 = pa.w;
        float l0 = el[s0 * HEADS + h], l1 = el[s1 * HEADS + h];
        float l2 = el[s2 * HEADS + h], l3 = el[s3 * HEADS + h];
        ushort4 f0 = *(const ushort4*)(featb + ((size_t)s0 << 8) + col);
        ushort4 f1 = *(const ushort4*)(featb + ((size_t)s1 << 8) + col);
        ushort4 f2 = *(const ushort4*)(featb + ((size_t)s2 << 8) + col);
        ushort4 f3 = *(const ushort4*)(featb + ((size_t)s3 << 8) + col);
        float v0 = l0 + erh, v1 = l1 + erh, v2 = l2 + erh, v3 = l3 + erh;
        v0 = v0 > 0.f ? v0 : NEG_SLOPE * v0;
        v1 = v1 > 0.f ? v1 : NEG_SLOPE * v1;
        v2 = v2 > 0.f ? v2 : NEG_SLOPE * v2;
        v3 = v3 > 0.f ? v3 : NEG_SLOPE * v3;
        float e0 = __expf(v0), e1 = __expf(v1);
        float e2 = __expf(v2), e3 = __expf(v3);
        dh += (e0 + e1) + (e2 + e3);
        ax += e0 * bf2f(f0.x) + e1 * bf2f(f1.x) + e2 * bf2f(f2.x) + e3 * bf2f(f3.x);
        ay += e0 * bf2f(f0.y) + e1 * bf2f(f1.y) + e2 * bf2f(f2.y) + e3 * bf2f(f3.y);
        az += e0 * bf2f(f0.z) + e1 * bf2f(f1.z) + e2 * bf2f(f2.z) + e3 * bf2f(f3.z);
        aw += e0 * bf2f(f0.w) + e1 * bf2f(f1.w) + e2 * bf2f(f2.w) + e3 * bf2f(f3.w);
    }
    while (p < end) { AGG_ONE(perm_src[p]); ++p; }

    float inv = 1.f / dh;
    float rx = ax * inv, ry = ay * inv, rz = az * inv, rw = aw * inv;
    rx += __shfl_xor(rx, 16); ry += __shfl_xor(ry, 16);
    rz += __shfl_xor(rz, 16); rw += __shfl_xor(rw, 16);
    rx += __shfl_xor(rx, 32); ry += __shfl_xor(ry, 32);
    rz += __shfl_xor(rz, 32); rw += __shfl_xor(rw, 32);
    if (lane < 16) {
        *(float4*)(out + (size_t)wid * HID + lane * 4) =
            make_float4(0.25f * rx, 0.25f * ry, 0.25f * rz, 0.25f * rw);
    }
}

extern "C" void kernel_launch(void* const* d_in, const int* in_sizes, int n_in,
                              void* d_out, int out_size, void* d_ws, size_t ws_size,
                              hipStream_t stream) {
    const float* x      = (const float*)d_in[0];
    const float* W      = (const float*)d_in[1];
    const float* attn_l = (const float*)d_in[2];
    const float* attn_r = (const float*)d_in[3];
    const int*   src    = (const int*)d_in[4];
    const int*   dst    = (const int*)d_in[5];
    float* out = (float*)d_out;

    int N = in_sizes[0] / IN_DIM;   // 50000
    int E = in_sizes[4];            // 800000

    // workspace layout (all sections 16B-aligned)
    unsigned short* xb    = (unsigned short*)d_ws;              // N*256 bf16
    unsigned short* wtp   = xb + (size_t)N * IN_DIM;            // 256*256 bf16
    unsigned short* featb = wtp + 256 * 256;                    // N*256 bf16
    float* el        = (float*)(featb + (size_t)N * IN_DIM);    // N*4
    float* er        = el + (size_t)N * HEADS;                  // N*4
    int*   count     = (int*)(er + (size_t)N * HEADS);          // N
    int*   row_start = count + N;                               // N+1 (+pad)
    int*   cursor    = row_start + N + 4;                       // N
    int*   bsum      = cursor + N;                              // <=256 (+pad)
    int*   perm_src  = bsum + 512;                              // E

    int NB = (N + 1 + 255) / 256;   // 196 — must stay <= 256 (P3 offset reduce)
    int n8 = N * IN_DIM / 8;

    // 0. cooperative plumbing (zero | casts+hist | blocksums | scan | scatter)
    int maxB = 0;
    int pgrid = 1024;
    if (hipOccupancyMaxActiveBlocksPerMultiprocessor(&maxB, plumbing_kernel, 256, 0)
            == hipSuccess && maxB > 0) {
        int cap = maxB * 256;             // 256 CUs on MI355X
        if (cap < pgrid) pgrid = cap;
    }
    if (pgrid < 256) pgrid = 256;         // still >= NB
    {
        void* args[] = { (void*)&x, (void*)&xb, (void*)&n8, (void*)&W, (void*)&wtp,
                         (void*)&src, (void*)&dst, (void*)&count, (void*)&bsum,
                         (void*)&row_start, (void*)&cursor, (void*)&perm_src,
                         (void*)&N, (void*)&E, (void*)&NB };
        hipLaunchCooperativeKernel((void*)plumbing_kernel, dim3(pgrid), dim3(256),
                                   args, 0, stream);
    }

    // 1. MFMA GEMM + fused el/er
    mfma_gemm_kernel<<<(N + BM - 1) / BM, 256, 0, stream>>>(
        xb, wtp, attn_l, attn_r, featb, el, er, N);

    // 2. fused softmax + aggregate
    node_aggregate_kernel<<<(N * 64 + 255) / 256, 256, 0, stream>>>(
        featb, el, er, row_start, perm_src, out, N);
}

// Round 7
// 280.305 us; speedup vs baseline: 2.3133x; 2.3133x over previous
//
#include <hip/hip_runtime.h>
#include <hip/hip_bf16.h>

#define IN_DIM 256
#define HEADS 4
#define HID 64
#define NEG_SLOPE 0.2f

typedef float f32x4 __attribute__((ext_vector_type(4)));
typedef short bf16x8 __attribute__((ext_vector_type(8)));
typedef unsigned short u16x8 __attribute__((ext_vector_type(8)));

__device__ __forceinline__ unsigned short f2bf(float f) {
    unsigned u = __float_as_uint(f);
    unsigned r = u + 0x7fffu + ((u >> 16) & 1u);   // RNE
    return (unsigned short)(r >> 16);
}
__device__ __forceinline__ float bf2f(unsigned short b) {
    return __uint_as_float(((unsigned)b) << 16);
}
__device__ __forceinline__ unsigned short f2h(float f) {
    _Float16 h = (_Float16)f;
    unsigned short u; __builtin_memcpy(&u, &h, 2); return u;
}
__device__ __forceinline__ float h2f(unsigned short u) {
    _Float16 h; __builtin_memcpy(&h, &u, 2); return (float)h;
}
__device__ __forceinline__ float esel(const int4& q, int h) {
    int w = (h & 2) ? q.z : q.y;
    unsigned short u = (unsigned short)((h & 1) ? (w >> 16) : (w & 0xffff));
    return h2f(u);
}
__device__ __forceinline__ void gload16(const void* g, void* l) {
    __builtin_amdgcn_global_load_lds(
        (const __attribute__((address_space(1))) unsigned int*)g,
        (__attribute__((address_space(3))) unsigned int*)l, 16, 0, 0);
}

// ---------- D1: zero count + cast x -> bf16 + cast/transpose W ----------
__global__ __launch_bounds__(256) void prep0_kernel(
        const float* __restrict__ x, unsigned short* __restrict__ xb, int n8,
        const float* __restrict__ W, unsigned short* __restrict__ wt,
        int* __restrict__ count, int N) {
    const int gsz = gridDim.x * 256;
    const int g0 = blockIdx.x * 256 + threadIdx.x;
    for (int i = g0; i < N; i += gsz) count[i] = 0;
    for (int i = g0; i < n8; i += gsz) {
        const float4* p = (const float4*)x + (size_t)i * 2;
        float4 a = p[0], b = p[1];
        u16x8 o;
        o[0] = f2bf(a.x); o[1] = f2bf(a.y); o[2] = f2bf(a.z); o[3] = f2bf(a.w);
        o[4] = f2bf(b.x); o[5] = f2bf(b.y); o[6] = f2bf(b.z); o[7] = f2bf(b.w);
        *(u16x8*)(xb + (size_t)i * 8) = o;
    }
    for (int i = g0; i < 256 * 256; i += gsz) {
        int n = i & 255, k = i >> 8;
        wt[n * 256 + k] = f2bf(W[k * 256 + n]);
    }
}

// ---------- D2: MFMA GEMM + fused el/er  UNION  dst-histogram ----------
// blocks [0,GB): GEMM (BM=64 rows, full 256-col width; wave wv = head wv,
// el/er from f32 acc in epilogue). blocks [GB, GB+HB): grid-stride hist
// (needs only D1's zeroed count — independent of GEMM work).
#define BM 64
#define BK 64
__global__ __launch_bounds__(256) void gemm_hist_kernel(
        const unsigned short* __restrict__ xb, const unsigned short* __restrict__ wt,
        const float* __restrict__ attn_l, const float* __restrict__ attn_r,
        unsigned short* __restrict__ featb, float* __restrict__ el,
        float* __restrict__ er, int N, int GB,
        const int* __restrict__ dst, int* __restrict__ count, int E) {
    if ((int)blockIdx.x >= GB) {
        const int hsz = (gridDim.x - GB) * 256;
        for (int i = ((int)blockIdx.x - GB) * 256 + threadIdx.x; i < E; i += hsz)
            atomicAdd(&count[dst[i]], 1);
        return;
    }
    __shared__ unsigned short As[BM * BK];       // 8 KB
    __shared__ unsigned short Bs[256 * BK];      // 32 KB
    const int tid = threadIdx.x;
    const int lane = tid & 63;
    const int wv = tid >> 6;
    const int bm = blockIdx.x * BM;

    f32x4 acc[4][4] = {};

    for (int k0 = 0; k0 < IN_DIM; k0 += BK) {
        #pragma unroll
        for (int r = 0; r < 2; ++r) {
            int i = r * 256 + tid;
            int row = i >> 3, slot = (i & 7) ^ (row & 7);
            int grow = bm + row; if (grow >= N) grow = N - 1;
            gload16(xb + (size_t)grow * IN_DIM + k0 + slot * 8,
                    (char*)As + (size_t)(r * 256 + (wv << 6)) * 16);
        }
        #pragma unroll
        for (int r = 0; r < 8; ++r) {
            int i = r * 256 + tid;
            int row = i >> 3, slot = (i & 7) ^ (row & 7);
            gload16(wt + (size_t)row * IN_DIM + k0 + slot * 8,
                    (char*)Bs + (size_t)(r * 256 + (wv << 6)) * 16);
        }
        __syncthreads();
        #pragma unroll
        for (int kk = 0; kk < 2; ++kk) {
            const int k16 = kk * 4 + (lane >> 4);
            bf16x8 af[4], bg[4];
            #pragma unroll
            for (int m = 0; m < 4; ++m) {
                int row = m * 16 + (lane & 15);
                af[m] = *(const bf16x8*)((const char*)As + row * 128 + ((k16 ^ (row & 7)) << 4));
            }
            #pragma unroll
            for (int n = 0; n < 4; ++n) {
                int row = (wv << 6) + n * 16 + (lane & 15);
                bg[n] = *(const bf16x8*)((const char*)Bs + row * 128 + ((k16 ^ (row & 7)) << 4));
            }
            #pragma unroll
            for (int m = 0; m < 4; ++m)
                #pragma unroll
                for (int n = 0; n < 4; ++n)
                    acc[m][n] = __builtin_amdgcn_mfma_f32_16x16x32_bf16(af[m], bg[n], acc[m][n], 0, 0, 0);
        }
        __syncthreads();
    }

    const int c15 = lane & 15;
    float al0 = attn_l[(wv << 6) + c15],      ar0 = attn_r[(wv << 6) + c15];
    float al1 = attn_l[(wv << 6) + 16 + c15], ar1 = attn_r[(wv << 6) + 16 + c15];
    float al2 = attn_l[(wv << 6) + 32 + c15], ar2 = attn_r[(wv << 6) + 32 + c15];
    float al3 = attn_l[(wv << 6) + 48 + c15], ar3 = attn_r[(wv << 6) + 48 + c15];

    #pragma unroll
    for (int m = 0; m < 4; ++m) {
        #pragma unroll
        for (int j = 0; j < 4; ++j) {
            int row = bm + m * 16 + ((lane >> 4) << 2) + j;
            bool ok = row < N;
            if (ok) {
                #pragma unroll
                for (int n = 0; n < 4; ++n)
                    featb[(size_t)row * IN_DIM + (wv << 6) + n * 16 + c15] = f2bf(acc[m][n][j]);
            }
            float pl = acc[m][0][j] * al0 + acc[m][1][j] * al1 + acc[m][2][j] * al2 + acc[m][3][j] * al3;
            float pr = acc[m][0][j] * ar0 + acc[m][1][j] * ar1 + acc[m][2][j] * ar2 + acc[m][3][j] * ar3;
            #pragma unroll
            for (int off = 1; off < 16; off <<= 1) {
                pl += __shfl_xor(pl, off);
                pr += __shfl_xor(pr, off);
            }
            if (ok && c15 == 0) {
                el[row * HEADS + wv] = pl;
                er[row * HEADS + wv] = pr;
            }
        }
    }
}

// ---------- D3: single-dispatch scan (each block recomputes its prefix) ----
__global__ __launch_bounds__(256) void scan_kernel(
        const int* __restrict__ count, int* __restrict__ row_start,
        int* __restrict__ cursor, int N) {
    __shared__ int ws[4];
    __shared__ int boff_s;
    const int c = blockIdx.x;
    const int tid = threadIdx.x, lane = tid & 63, wv = tid >> 6;
    // block offset = sum count[0 .. c*256)
    int lim = c * 256; if (lim > N) lim = N;
    int acc = 0;
    for (int j = tid; j < lim; j += 256) acc += count[j];
    #pragma unroll
    for (int off = 1; off < 64; off <<= 1) acc += __shfl_xor(acc, off);
    if (lane == 0) ws[wv] = acc;
    __syncthreads();
    if (tid == 0) boff_s = ws[0] + ws[1] + ws[2] + ws[3];
    __syncthreads();
    // local exclusive scan of this chunk
    int i = c * 256 + tid;
    int v = (i < N) ? count[i] : 0;
    int incl = v;
    #pragma unroll
    for (int off = 1; off < 64; off <<= 1) {
        int t = __shfl_up(incl, off);
        if (lane >= off) incl += t;
    }
    if (lane == 63) ws[wv] = incl;
    __syncthreads();
    int wofs = 0;
    #pragma unroll
    for (int w = 0; w < 4; ++w) if (w < wv) wofs += ws[w];
    int excl = boff_s + wofs + incl - v;
    if (i < N) { row_start[i] = excl; cursor[i] = excl; }
    else if (i == N) row_start[N] = excl;
}

// ---------- D4: scatter + edge-score precompute ----------
// One thread per edge: gather el[src], er[dst] (L2-hot, 800KB each),
// leaky_relu + exp ONCE per (edge,head), pack 4 fp16 exps + src into 16B.
__global__ __launch_bounds__(256) void scatter_score_kernel(
        const int* __restrict__ src, const int* __restrict__ dst,
        const float* __restrict__ el, const float* __restrict__ er,
        int* __restrict__ cursor, int4* __restrict__ pay, int E) {
    int i = blockIdx.x * 256 + threadIdx.x;
    if (i >= E) return;
    int s = src[i], d = dst[i];
    float4 l = ((const float4*)el)[s];
    float4 r = ((const float4*)er)[d];
    float v0 = l.x + r.x, v1 = l.y + r.y, v2 = l.z + r.z, v3 = l.w + r.w;
    v0 = v0 > 0.f ? v0 : NEG_SLOPE * v0;
    v1 = v1 > 0.f ? v1 : NEG_SLOPE * v1;
    v2 = v2 > 0.f ? v2 : NEG_SLOPE * v2;
    v3 = v3 > 0.f ? v3 : NEG_SLOPE * v3;
    int e01 = (int)f2h(__expf(v0)) | ((int)f2h(__expf(v1)) << 16);
    int e23 = (int)f2h(__expf(v2)) | ((int)f2h(__expf(v3)) << 16);
    int pos = atomicAdd(&cursor[d], 1);
    pay[pos] = make_int4(s, e01, e23, 0);
}

// ---------- D5: fused softmax-normalize + aggregate ----------
// One wave per dst node; lane=(h=lane>>4, q=lane&15). Per edge: one 16B
// broadcast payload + one ushort4 (8B/lane, 512B/wave) coalesced feat row.
// exp/el-gather already done in D4. Head-mean via xor butterfly.
#define AGG_ONE(Q) do {                                             \
    float e_ = esel((Q), h);                                        \
    dh += e_;                                                       \
    ushort4 fv_ = *(const ushort4*)(featb + ((size_t)(Q).x << 8) + col); \
    ax += e_ * bf2f(fv_.x); ay += e_ * bf2f(fv_.y);                 \
    az += e_ * bf2f(fv_.z); aw += e_ * bf2f(fv_.w); } while (0)

__global__ __launch_bounds__(256) void node_aggregate_kernel(
        const unsigned short* __restrict__ featb, const int4* __restrict__ pay,
        const int* __restrict__ row_start, float* __restrict__ out, int N) {
    int wid = blockIdx.x * 4 + (threadIdx.x >> 6);
    int lane = threadIdx.x & 63;
    if (wid >= N) return;
    const int beg = row_start[wid], end = row_start[wid + 1];
    if (beg == end) {
        if (lane < 16) *(float4*)(out + (size_t)wid * HID + lane * 4) = make_float4(0.f, 0.f, 0.f, 0.f);
        return;
    }
    const int h = lane >> 4;
    const int col = lane * 4;

    float dh = 0.f, ax = 0.f, ay = 0.f, az = 0.f, aw = 0.f;
    int p = beg;
    for (; p + 4 <= end; p += 4) {
        int4 q0 = pay[p], q1 = pay[p + 1], q2 = pay[p + 2], q3 = pay[p + 3];
        float e0 = esel(q0, h), e1 = esel(q1, h), e2 = esel(q2, h), e3 = esel(q3, h);
        ushort4 f0 = *(const ushort4*)(featb + ((size_t)q0.x << 8) + col);
        ushort4 f1 = *(const ushort4*)(featb + ((size_t)q1.x << 8) + col);
        ushort4 f2 = *(const ushort4*)(featb + ((size_t)q2.x << 8) + col);
        ushort4 f3 = *(const ushort4*)(featb + ((size_t)q3.x << 8) + col);
        dh += (e0 + e1) + (e2 + e3);
        ax += e0 * bf2f(f0.x) + e1 * bf2f(f1.x) + e2 * bf2f(f2.x) + e3 * bf2f(f3.x);
        ay += e0 * bf2f(f0.y) + e1 * bf2f(f1.y) + e2 * bf2f(f2.y) + e3 * bf2f(f3.y);
        az += e0 * bf2f(f0.z) + e1 * bf2f(f1.z) + e2 * bf2f(f2.z) + e3 * bf2f(f3.z);
        aw += e0 * bf2f(f0.w) + e1 * bf2f(f1.w) + e2 * bf2f(f2.w) + e3 * bf2f(f3.w);
    }
    for (; p < end; ++p) { int4 q = pay[p]; AGG_ONE(q); }

    float inv = 1.f / dh;
    float rx = ax * inv, ry = ay * inv, rz = az * inv, rw = aw * inv;
    rx += __shfl_xor(rx, 16); ry += __shfl_xor(ry, 16);
    rz += __shfl_xor(rz, 16); rw += __shfl_xor(rw, 16);
    rx += __shfl_xor(rx, 32); ry += __shfl_xor(ry, 32);
    rz += __shfl_xor(rz, 32); rw += __shfl_xor(rw, 32);
    if (lane < 16) {
        *(float4*)(out + (size_t)wid * HID + lane * 4) =
            make_float4(0.25f * rx, 0.25f * ry, 0.25f * rz, 0.25f * rw);
    }
}

extern "C" void kernel_launch(void* const* d_in, const int* in_sizes, int n_in,
                              void* d_out, int out_size, void* d_ws, size_t ws_size,
                              hipStream_t stream) {
    const float* x      = (const float*)d_in[0];
    const float* W      = (const float*)d_in[1];
    const float* attn_l = (const float*)d_in[2];
    const float* attn_r = (const float*)d_in[3];
    const int*   src    = (const int*)d_in[4];
    const int*   dst    = (const int*)d_in[5];
    float* out = (float*)d_out;

    const int N = in_sizes[0] / IN_DIM;   // 50000
    const int E = in_sizes[4];            // 800000

    // workspace layout (16B-aligned sections).
    // pay ALIASES xb: xb is written in D1, consumed by D2 (GEMM); pay is
    // written in D4 and read in D5 — lifetimes are disjoint in stream order.
    unsigned short* xb    = (unsigned short*)d_ws;              // N*256 bf16
    unsigned short* wtp   = xb + (size_t)N * IN_DIM;            // 256*256 bf16
    unsigned short* featb = wtp + 256 * 256;                    // N*256 bf16
    float* el        = (float*)(featb + (size_t)N * IN_DIM);    // N*4
    float* er        = el + (size_t)N * HEADS;                  // N*4
    int*   count     = (int*)(er + (size_t)N * HEADS);          // N
    int*   row_start = count + N;                               // N+1 (+pad)
    int*   cursor    = row_start + N + 4;                       // N
    int4*  pay       = (int4*)xb;                               // E x 16B (alias)

    const int NB = (N + 1 + 255) / 256;   // covers index N for row_start[N]
    const int n8 = N * IN_DIM / 8;
    const int GB = (N + BM - 1) / BM;     // 782 GEMM blocks
    const int HB = 256;                   // hist blocks

    // D1: zero count + cast x + cast/transpose W
    prep0_kernel<<<2048, 256, 0, stream>>>(x, xb, n8, W, wtp, count, N);

    // D2: GEMM(+el/er)  ∪  dst histogram
    gemm_hist_kernel<<<GB + HB, 256, 0, stream>>>(
        xb, wtp, attn_l, attn_r, featb, el, er, N, GB, dst, count, E);

    // D3: scan -> row_start, cursor
    scan_kernel<<<NB, 256, 0, stream>>>(count, row_start, cursor, N);

    // D4: scatter + edge-score precompute (fp16 exps packed with src)
    scatter_score_kernel<<<(E + 255) / 256, 256, 0, stream>>>(
        src, dst, el, er, cursor, pay, E);

    // D5: fused normalize + aggregate
    node_aggregate_kernel<<<(N * 64 + 255) / 256, 256, 0, stream>>>(
        featb, pay, row_start, out, N);
}